// Round 4
// baseline (160.427 us; speedup 1.0000x reference)
//
#include <hip/hip_runtime.h>
#include <hip/hip_bf16.h>
#include <stdint.h>

#define B_  2
#define S_  2048
#define H_  512
#define NH_ 8
#define DK_ 64

typedef __bf16 bf16x8 __attribute__((ext_vector_type(8)));
typedef short  s16x4  __attribute__((ext_vector_type(4)));
typedef float  f32x4  __attribute__((ext_vector_type(4)));

static __device__ __forceinline__ uint32_t pk2(float a, float b) {
  __hip_bfloat162 h = __float22bfloat162_rn(float2{a, b});
  uint32_t u;
  __builtin_memcpy(&u, &h, 4);
  return u;
}

// 16x16x16 bf16 MFMA. Guard with __HIP_DEVICE_COMPILE__ (host pass lacks
// device builtins — R3 compile failure).
static __device__ __forceinline__ f32x4 mfma_k16(s16x4 a, s16x4 b, f32x4 c) {
#if defined(__HIP_DEVICE_COMPILE__)
  return __builtin_amdgcn_mfma_f32_16x16x16bf16_1k(a, b, c, 0, 0, 0);
#else
  (void)a; (void)b;
  return c;
#endif
}

typedef const __attribute__((address_space(1))) uint32_t* gas_t;
typedef __attribute__((address_space(3))) uint32_t* las_t;
static __device__ __forceinline__ void cp16(const void* g, void* l) {
  __builtin_amdgcn_global_load_lds((gas_t)g, (las_t)l, 16, 0, 0);
}

// ---------------------------------------------------------------------------
// Kernel 1 (fused): proj (blocks 0..383, XCD-swizzled) + bias zero-scan
// (384..895) + fmL (896).
// R11: proj retiled 128x64 -> 128x128 (384 blocks). Halves the f32->bf16
// pack VALU work (proj's dominant cost) and X L2 re-reads (8x -> 4x).
// ---------------------------------------------------------------------------
struct ProjArgs {
  const float* X[3];
  const float* W[3];
  const float* Bv[3];
  uint16_t*    O[3];
  const float* bias;
  const int*   mask;
  uint32_t*    zrow;
  float*       fmL;
};

__global__ __launch_bounds__(256) void prep_proj_kernel(ProjArgs pa) {
  __shared__ __align__(16) char psm[32768];
  int bid = blockIdx.x, t = threadIdx.x;

  if (bid >= 384) {
    if (bid < 896) {
      // ---- bias zero-scan: 8 (b,q) rows per block, loads pipelined ----
      int rr = bid - 384;                      // 0..511
      const float* base = pa.bias + (size_t)rr * 8 * 2048 + t * 8;
      uint4 a[8], b2[8];
#pragma unroll
      for (int i = 0; i < 8; i++) {
        const uint4* src = (const uint4*)(base + (size_t)i * 2048);
        a[i] = src[0]; b2[i] = src[1];
      }
      uint32_t (*wbuf)[4] = (uint32_t (*)[4])psm;   // [row][wave]
      int wv = t >> 6, ln = t & 63;
#pragma unroll
      for (int i = 0; i < 8; i++) {
        bool z = ((a[i].x << 1) == 0u) | ((a[i].y << 1) == 0u) |
                 ((a[i].z << 1) == 0u) | ((a[i].w << 1) == 0u) |
                 ((b2[i].x << 1) == 0u) | ((b2[i].y << 1) == 0u) |
                 ((b2[i].z << 1) == 0u) | ((b2[i].w << 1) == 0u);
        uint64_t m = __ballot(z);
        if (ln == 0) {
          uint32_t bits = 0;
#pragma unroll
          for (int c = 0; c < 8; c++)
            bits |= (uint32_t)(((m >> (8 * c)) & 0xFFull) != 0ull) << c;
          wbuf[i][wv] = bits;                  // chunks [wv*8, wv*8+8)
        }
      }
      __syncthreads();
      if (t < 8)
        pa.zrow[rr * 8 + t] = wbuf[t][0] | (wbuf[t][1] << 8) |
                              (wbuf[t][2] << 16) | (wbuf[t][3] << 24);
    } else {
      // ---- fmL = mask * log2(e) ----
      const float LOG2E = 1.44269504088896340736f;
#pragma unroll
      for (int i = 0; i < 16; i++) {
        int idx = i * 256 + t;
        pa.fmL[idx] = (float)pa.mask[idx] * LOG2E;
      }
    }
    return;
  }

  // ---- proj: y = x @ W^T + b, tile 128 s x 128 d ----
  // XCD swizzle: all 4 dtiles of group gi=(mat,mtile) get bids == gi (mod 8)
  // -> same XCD -> X tile fetched into one L2, read 4x from there.
  int xcd = bid & 7, j = bid >> 3;             // j in 0..47
  int gi = ((j >> 2) << 3) | xcd;              // group 0..95
  int dtile = j & 3;
  int mat = gi >> 5, mtile = gi & 31;
  int m0 = mtile * 128, n0 = dtile * 128;
  const float* X  = pa.X[mat];
  const float* Wt = pa.W[mat];
  const float* Bv = pa.Bv[mat];
  uint16_t*    O  = pa.O[mat];

  uint16_t (*Xs)[64] = (uint16_t (*)[64])psm;             // [128][64] 16 KB
  uint16_t (*Ws)[64] = (uint16_t (*)[64])(psm + 16384);   // [128][64] 16 KB

  int w = t >> 6, l = t & 63, lo = l & 15, g = l >> 4;
  int lr = l >> 4;          // 0..3 row-in-group (16 lanes per row)
  int lc = l & 15;          // 16B column chunk within the 256B row segment

  // coalesced staging bases: lane covers float cols [lc*4, lc*4+4)
  const float* Xp = X + (size_t)(m0 + w * 32 + lr) * 512 + lc * 4;
  const float* Wp = Wt + (size_t)(n0 + w * 32 + lr) * 512 + lc * 4;

  f32x4 acc[2][8];
#pragma unroll
  for (int st = 0; st < 2; st++)
#pragma unroll
    for (int dt = 0; dt < 8; dt++) acc[st][dt] = (f32x4){0.f, 0.f, 0.f, 0.f};

  float4 xa[8], wa2[8];
#pragma unroll
  for (int i = 0; i < 8; i++) xa[i] = *(const float4*)(Xp + (size_t)i * 4 * 512);
#pragma unroll
  for (int i = 0; i < 8; i++) wa2[i] = *(const float4*)(Wp + (size_t)i * 4 * 512);

  for (int kb = 0; kb < 8; kb++) {
    // pack current registers -> LDS (bf16), b64 per row-chunk.
    // row-major, 16B segs XOR'd by row&7.
#pragma unroll
    for (int i = 0; i < 8; i++) {
      int r = w * 32 + i * 4 + lr;
      int s0 = (lc >> 1) ^ (r & 7);
      uint2 pk{pk2(xa[i].x, xa[i].y), pk2(xa[i].z, xa[i].w)};
      *(uint2*)&Xs[r][s0 * 8 + (lc & 1) * 4] = pk;
    }
#pragma unroll
    for (int i = 0; i < 8; i++) {
      int r = w * 32 + i * 4 + lr;
      int s0 = (lc >> 1) ^ (r & 7);
      uint2 pk{pk2(wa2[i].x, wa2[i].y), pk2(wa2[i].z, wa2[i].w)};
      *(uint2*)&Ws[r][s0 * 8 + (lc & 1) * 4] = pk;
    }
    __syncthreads();
    if (kb < 7) {
      const float* Xn = Xp + (kb + 1) * 64;
      const float* Wn = Wp + (kb + 1) * 64;
#pragma unroll
      for (int i = 0; i < 8; i++) xa[i] = *(const float4*)(Xn + (size_t)i * 4 * 512);
#pragma unroll
      for (int i = 0; i < 8; i++) wa2[i] = *(const float4*)(Wn + (size_t)i * 4 * 512);
    }
#pragma unroll
    for (int kk = 0; kk < 2; kk++) {
      int seg = (kk * 4 + g) ^ (lo & 7);
      bf16x8 xf[2], wf[8];
#pragma unroll
      for (int st = 0; st < 2; st++)
        xf[st] = *(const bf16x8*)&Xs[w * 32 + st * 16 + lo][seg * 8];
#pragma unroll
      for (int dt = 0; dt < 8; dt++)
        wf[dt] = *(const bf16x8*)&Ws[dt * 16 + lo][seg * 8];
      if (mat < 2) {
#pragma unroll
        for (int st = 0; st < 2; st++)
#pragma unroll
          for (int dt = 0; dt < 8; dt++)
            acc[st][dt] = __builtin_amdgcn_mfma_f32_16x16x32_bf16(wf[dt], xf[st], acc[st][dt], 0, 0, 0);
      } else {
#pragma unroll
        for (int st = 0; st < 2; st++)
#pragma unroll
          for (int dt = 0; dt < 8; dt++)
            acc[st][dt] = __builtin_amdgcn_mfma_f32_16x16x32_bf16(xf[st], wf[dt], acc[st][dt], 0, 0, 0);
      }
    }
    __syncthreads();
  }

  if (mat < 2) {
    float scale = (mat == 0) ? 0.125f : 1.0f;
    float4 bv4[8];
#pragma unroll
    for (int dt = 0; dt < 8; dt++)
      bv4[dt] = *(const float4*)(Bv + n0 + dt * 16 + g * 4);
#pragma unroll
    for (int st = 0; st < 2; st++) {
      int ss = m0 + w * 32 + st * 16 + lo;
      int bb = ss >> 11, sIn = ss & 2047;
#pragma unroll
      for (int dt = 0; dt < 8; dt++) {
        int h2 = dtile * 2 + (dt >> 2);        // output head
        uint16_t* op = O + ((size_t)(bb * NH_ + h2) * S_ + sIn) * DK_ +
                       (dt & 3) * 16 + g * 4;
        float v0 = (acc[st][dt][0] + bv4[dt].x) * scale;
        float v1 = (acc[st][dt][1] + bv4[dt].y) * scale;
        float v2 = (acc[st][dt][2] + bv4[dt].z) * scale;
        float v3 = (acc[st][dt][3] + bv4[dt].w) * scale;
        uint2 pk{pk2(v0, v1), pk2(v2, v3)};
        *(uint2*)op = pk;
      }
    }
  } else {
    float bval[8];
#pragma unroll
    for (int dt = 0; dt < 8; dt++) bval[dt] = Bv[n0 + dt * 16 + lo];
#pragma unroll
    for (int st = 0; st < 2; st++) {
      int m = m0 + w * 32 + st * 16 + g * 4;
      int bb = m >> 11, sIn = m & 2047;
#pragma unroll
      for (int dt = 0; dt < 8; dt++) {
        int h2 = dtile * 2 + (dt >> 2);        // output head
        int dd = (dt & 3) * 16 + lo;
        float v0 = acc[st][dt][0] + bval[dt];
        float v1 = acc[st][dt][1] + bval[dt];
        float v2 = acc[st][dt][2] + bval[dt];
        float v3 = acc[st][dt][3] + bval[dt];
        uint2 pk{pk2(v0, v1), pk2(v2, v3)};
        *(uint2*)(O + ((size_t)(bb * NH_ + h2) * DK_ + dd) * S_ + sIn) = pk;
      }
    }
  }
}

// ---------------------------------------------------------------------------
// Kernel 2: flash attention (R10 geometry: q-tile 64, grid 512, 2 blocks/CU).
// R11: softmax row-sum folded into the matrix pipe via ones-vector MFMA:
// ts[q] = sum_k P[k][q] = mfma_k16(ones, pf, tsa) (A=1 makes every output
// row the column sum; any reg of tsa holds ts for q=qt*16+lo). Removes 16
// v_add per wave-tile from the VALU (the busiest pipe), the ts dep chain,
// and the epilogue shfl reduce; denominator now sums the SAME bf16-rounded
// p that PV uses (more self-consistent numerics).
// R9/R10 lessons: schedule + tiling variants are neutral — instr diet only.
// ---------------------------------------------------------------------------
__global__ __launch_bounds__(256) void attn_kernel(
    const uint16_t* __restrict__ Qb, const uint16_t* __restrict__ Kb,
    const uint16_t* __restrict__ Vt, const uint32_t* __restrict__ zrow,
    const float* __restrict__ fmL, const float* __restrict__ bias,
    float* __restrict__ out) {
  int bid = blockIdx.x;
  int bh = bid & 15, qtile = bid >> 4;   // 512 blocks: bid%8 const per bh
  int b = bh >> 3, h = bh & 7;
  int q0 = qtile * 64;
  int t = threadIdx.x;
  int w = t >> 6, l = t & 63, lo = l & 15, g = l >> 4;

  __shared__ __align__(16) char smem[32768];
  uint16_t* KsB = (uint16_t*)smem;             // [2][64 k][64 d] 16 KB
  uint16_t* VsB = (uint16_t*)(smem + 16384);   // [2][64 d][64 k] 16 KB

  const uint16_t* Qh = Qb + (size_t)bh * S_ * DK_;
  const uint16_t* Kh = Kb + (size_t)bh * S_ * DK_;
  const uint16_t* Vh = Vt + (size_t)bh * DK_ * S_;

  // DMA: lane l -> LDS row w*16 + l/8, seg l&7; global seg = (l&7)^(row&7).
  int lrow = l >> 3, lseg = (l & 7) ^ lrow;
  const uint16_t* kbase = Kh + (size_t)(w * 16 + lrow) * DK_ + lseg * 8;
  const uint16_t* vbase = Vh + (size_t)(w * 16 + lrow) * S_ + lseg * 8;
  uint16_t* kd0 = KsB + (w * 16) * 64;
  uint16_t* kd8 = KsB + (w * 16 + 8) * 64;
  uint16_t* vd0 = VsB + (w * 16) * 64;
  uint16_t* vd8 = VsB + (w * 16 + 8) * 64;

  // block-uniform zero-bias mask (OR over this block's 64 q rows)
  uint32_t zall = zrow[(b << 11) + q0 + l];
#pragma unroll
  for (int s = 1; s < 64; s <<= 1) zall |= __shfl_xor(zall, s);

  // Register-resident Q fragments (B-operand of QK), 4 q-subtiles x K=64.
  bf16x8 qf[4][2];
#pragma unroll
  for (int qt = 0; qt < 4; qt++)
#pragma unroll
    for (int kk = 0; kk < 2; kk++)
      qf[qt][kk] = *(const bf16x8*)(Qh + (size_t)(q0 + qt * 16 + lo) * DK_ + kk * 32 + g * 8);

  f32x4 o[4][4];
#pragma unroll
  for (int dt = 0; dt < 4; dt++)
#pragma unroll
    for (int qt = 0; qt < 4; qt++) o[dt][qt] = (f32x4){0.f, 0.f, 0.f, 0.f};
  f32x4 tsa[4];
#pragma unroll
  for (int qt = 0; qt < 4; qt++) tsa[qt] = (f32x4){0.f, 0.f, 0.f, 0.f};
  const s16x4 vone = {(short)0x3F80, (short)0x3F80, (short)0x3F80, (short)0x3F80};

  const float* fmrow = fmL + b * S_ + w * 16 + g * 4;
  const float LOG2E = 1.44269504088896340736f;

  // stage tile 0
  cp16(kbase, kd0);
  cp16(kbase + 512, kd8);
  cp16(vbase, vd0);
  cp16(vbase + 8 * S_, vd8);
  float4 mvc = *(const float4*)(fmrow);
  float4 mvn = mvc;

  for (int kb = 0; kb < 32; kb++) {
    int cur = kb & 1;
    int k0 = kb * 64;
    // my tile-kb DMAs were issued a full iteration ago -> complete by now.
    asm volatile("s_waitcnt vmcnt(0)" ::: "memory");
    __builtin_amdgcn_s_barrier();               // publish tile kb to all waves
    if (kb + 1 < 32) {                          // prefetch tile kb+1 (in
      int kn = k0 + 64;                         // flight across this compute)
      int nb = (cur ^ 1) * 4096;
      cp16(kbase + (size_t)kn * 64, kd0 + nb);
      cp16(kbase + (size_t)kn * 64 + 512, kd8 + nb);
      cp16(vbase + kn, vd0 + nb);
      cp16(vbase + kn + 8 * S_, vd8 + nb);
      mvn = *(const float4*)(fmrow + kn);
    }
    __builtin_amdgcn_sched_barrier(0);          // pin: no ds_read above barrier

    const uint16_t* KsT = KsB + cur * 4096;
    const uint16_t* VsT = VsB + cur * 4096;

    // V^T A-frags for PV
    s16x4 vf[4];
    {
      int s = (2 * w + (g >> 1)) ^ (lo & 7);
      int off = s * 8 + (g & 1) * 4;
#pragma unroll
      for (int dt = 0; dt < 4; dt++)
        vf[dt] = *(const s16x4*)(VsT + (dt * 16 + lo) * 64 + off);
    }
    // K A-frags (this wave's 16 k-rows)
    bf16x8 kf[2];
#pragma unroll
    for (int kk = 0; kk < 2; kk++) {
      int s = (kk * 4 + g) ^ (lo & 7);
      kf[kk] = *(const bf16x8*)(KsT + (w * 16 + lo) * 64 + s * 8);
    }

    // S^T = K * Q^T : lane holds S[k = w*16+g*4+r][q = qt*16+lo]
    f32x4 c[4];
#pragma unroll
    for (int qt = 0; qt < 4; qt++) {
      f32x4 z = {0.f, 0.f, 0.f, 0.f};
      z = __builtin_amdgcn_mfma_f32_16x16x32_bf16(kf[0], qf[qt][0], z, 0, 0, 0);
      c[qt] = __builtin_amdgcn_mfma_f32_16x16x32_bf16(kf[1], qf[qt][1], z, 0, 0, 0);
    }

    float4 mv4 = mvc;
    s16x4 pf[4];
    if (((zall >> kb) & 1u) == 0u) {   // no zero bias in this 64k chunk
#pragma unroll
      for (int qt = 0; qt < 4; qt++) {
        float p0 = __builtin_amdgcn_exp2f(__builtin_fmaf(c[qt][0], LOG2E, mv4.x));
        float p1 = __builtin_amdgcn_exp2f(__builtin_fmaf(c[qt][1], LOG2E, mv4.y));
        float p2 = __builtin_amdgcn_exp2f(__builtin_fmaf(c[qt][2], LOG2E, mv4.z));
        float p3 = __builtin_amdgcn_exp2f(__builtin_fmaf(c[qt][3], LOG2E, mv4.w));
        union { s16x4 v; uint32_t u[2]; } uu;
        uu.u[0] = pk2(p0, p1);
        uu.u[1] = pk2(p2, p3);
        pf[qt] = uu.v;
      }
    } else {                           // rare: bias==0 -> weight 0
#pragma unroll
      for (int qt = 0; qt < 4; qt++) {
        float4 bz = *(const float4*)(bias + ((size_t)(b * S_ + q0 + qt * 16 + lo)) * S_ + k0 + w * 16 + g * 4);
        float p0 = (bz.x == 0.f) ? 0.f : __builtin_amdgcn_exp2f(__builtin_fmaf(c[qt][0], LOG2E, mv4.x));
        float p1 = (bz.y == 0.f) ? 0.f : __builtin_amdgcn_exp2f(__builtin_fmaf(c[qt][1], LOG2E, mv4.y));
        float p2 = (bz.z == 0.f) ? 0.f : __builtin_amdgcn_exp2f(__builtin_fmaf(c[qt][2], LOG2E, mv4.z));
        float p3 = (bz.w == 0.f) ? 0.f : __builtin_amdgcn_exp2f(__builtin_fmaf(c[qt][3], LOG2E, mv4.w));
        union { s16x4 v; uint32_t u[2]; } uu;
        uu.u[0] = pk2(p0, p1);
        uu.u[1] = pk2(p2, p3);
        pf[qt] = uu.v;
      }
    }

    // row-sum via matrix pipe: tsa[qt][r] = sum_k pf[k][q=lo] (all r equal)
#pragma unroll
    for (int qt = 0; qt < 4; qt++)
      tsa[qt] = mfma_k16(vone, pf[qt], tsa[qt]);

    // PV: o[dt][qt] lane holds O[q=qt*16+lo][d=dt*16+g*4+r]
#pragma unroll
    for (int dt = 0; dt < 4; dt++)
#pragma unroll
      for (int qt = 0; qt < 4; qt++)
        o[dt][qt] = mfma_k16(vf[dt], pf[qt], o[dt][qt]);

    mvc = mvn;
  }

  // ---- epilogue: reduce 4 wave-partials, normalize, store (2 q-halves) ----
  float* OT = (float*)smem;               // [64 d][33] floats (8448 B)
  float* LS = (float*)(smem + 8448);      // [4 w][4 qt][16 lo] (1 KB)
  __syncthreads();                        // main-loop LDS reads complete
  if (g == 0) {
#pragma unroll
    for (int qt = 0; qt < 4; qt++) LS[(w * 4 + qt) * 16 + lo] = tsa[qt][0];
  }
#pragma unroll
  for (int qh = 0; qh < 2; qh++) {
#pragma unroll
    for (int ww = 0; ww < 4; ww++) {
      if (w == ww) {
#pragma unroll
        for (int dt = 0; dt < 4; dt++)
#pragma unroll
          for (int qt = 0; qt < 2; qt++)
#pragma unroll
            for (int r = 0; r < 4; r++) {
              int idx = (dt * 16 + g * 4 + r) * 33 + qt * 16 + lo;
              float val = o[dt][qh * 2 + qt][r];
              if (ww == 0) OT[idx] = val;
              else         OT[idx] += val;
            }
      }
      __syncthreads();
    }
    {
      int q = t >> 3, dseg = (t & 7) * 8;   // q in [0,32), 8 d per thread
      int qt2 = qh * 2 + (q >> 4), lo2 = q & 15;
      float lsum = LS[(0 * 4 + qt2) * 16 + lo2] + LS[(1 * 4 + qt2) * 16 + lo2] +
                   LS[(2 * 4 + qt2) * 16 + lo2] + LS[(3 * 4 + qt2) * 16 + lo2];
      float linv = 1.0f / fmaxf(lsum, 1e-30f);
      float* ob = out + ((size_t)(b * S_ + q0 + qh * 32 + q)) * H_ + h * DK_ + dseg;
#pragma unroll
      for (int i = 0; i < 2; i++) {
        float4 v;
        v.x = OT[(dseg + i * 4 + 0) * 33 + q] * linv;
        v.y = OT[(dseg + i * 4 + 1) * 33 + q] * linv;
        v.z = OT[(dseg + i * 4 + 2) * 33 + q] * linv;
        v.w = OT[(dseg + i * 4 + 3) * 33 + q] * linv;
        *(float4*)(ob + i * 4) = v;
      }
    }
    __syncthreads();                      // OT reads done before next overwrite
  }
}

// ---------------------------------------------------------------------------
extern "C" void kernel_launch(void* const* d_in, const int* in_sizes, int n_in,
                              void* d_out, int out_size, void* d_ws, size_t ws_size,
                              hipStream_t stream) {
  const float* query = (const float*)d_in[0];
  const float* key   = (const float*)d_in[1];
  const float* value = (const float*)d_in[2];
  const float* bias  = (const float*)d_in[3];
  const int*   mask  = (const int*)d_in[4];
  const float* Wq = (const float*)d_in[5];
  const float* bq = (const float*)d_in[6];
  const float* Wk = (const float*)d_in[7];
  const float* bk = (const float*)d_in[8];
  const float* Wv = (const float*)d_in[9];
  const float* bv = (const float*)d_in[10];

  char* ws = (char*)d_ws;
  uint32_t* zrow = (uint32_t*)ws;                             // 16 KB
  float*    fmL  = (float*)(ws + 16384);                      // 16 KB
  uint16_t* Qb = (uint16_t*)(ws + (size_t)(1 << 20));         // 4 MB
  uint16_t* Kb = (uint16_t*)(ws + (size_t)(5 << 20));         // 4 MB
  uint16_t* Vt = (uint16_t*)(ws + (size_t)(9 << 20));         // 4 MB

  ProjArgs pa;
  pa.X[0] = query; pa.X[1] = key; pa.X[2] = value;
  pa.W[0] = Wq;    pa.W[1] = Wk;  pa.W[2] = Wv;
  pa.Bv[0] = bq;   pa.Bv[1] = bk; pa.Bv[2] = bv;
  pa.O[0] = Qb;    pa.O[1] = Kb;  pa.O[2] = Vt;
  pa.bias = bias;  pa.mask = mask;
  pa.zrow = zrow;  pa.fmL = fmL;

  prep_proj_kernel<<<897, 256, 0, stream>>>(pa);

  attn_kernel<<<512, 256, 0, stream>>>(Qb, Kb, Vt, zrow, fmL, bias, (float*)d_out);
}

// Round 5
// 157.823 us; speedup vs baseline: 1.0165x; 1.0165x over previous
//
#include <hip/hip_runtime.h>
#include <hip/hip_bf16.h>
#include <stdint.h>

#define B_  2
#define S_  2048
#define H_  512
#define NH_ 8
#define DK_ 64

typedef __bf16 bf16x8 __attribute__((ext_vector_type(8)));
typedef short  s16x4  __attribute__((ext_vector_type(4)));
typedef float  f32x4  __attribute__((ext_vector_type(4)));

static __device__ __forceinline__ uint32_t pk2(float a, float b) {
  __hip_bfloat162 h = __float22bfloat162_rn(float2{a, b});
  uint32_t u;
  __builtin_memcpy(&u, &h, 4);
  return u;
}

// 16x16x16 bf16 MFMA. Guard with __HIP_DEVICE_COMPILE__ (host pass lacks
// device builtins — R3 compile failure).
static __device__ __forceinline__ f32x4 mfma_k16(s16x4 a, s16x4 b, f32x4 c) {
#if defined(__HIP_DEVICE_COMPILE__)
  return __builtin_amdgcn_mfma_f32_16x16x16bf16_1k(a, b, c, 0, 0, 0);
#else
  (void)a; (void)b;
  return c;
#endif
}

typedef const __attribute__((address_space(1))) uint32_t* gas_t;
typedef __attribute__((address_space(3))) uint32_t* las_t;
static __device__ __forceinline__ void cp16(const void* g, void* l) {
  __builtin_amdgcn_global_load_lds((gas_t)g, (las_t)l, 16, 0, 0);
}

// ---------------------------------------------------------------------------
// Kernel 1 (fused): proj (blocks 0..383, XCD-swizzled) + bias zero-scan
// (384..895) + fmL (896).
// R11: proj retiled 128x64 -> 128x128 (384 blocks). Halves the f32->bf16
// pack VALU work (proj's dominant cost) and X L2 re-reads (8x -> 4x).
// ---------------------------------------------------------------------------
struct ProjArgs {
  const float* X[3];
  const float* W[3];
  const float* Bv[3];
  uint16_t*    O[3];
  const float* bias;
  const int*   mask;
  uint32_t*    zrow;
  float*       fmL;
};

__global__ __launch_bounds__(256) void prep_proj_kernel(ProjArgs pa) {
  __shared__ __align__(16) char psm[32768];
  int bid = blockIdx.x, t = threadIdx.x;

  if (bid >= 384) {
    if (bid < 896) {
      // ---- bias zero-scan: 8 (b,q) rows per block, loads pipelined ----
      int rr = bid - 384;                      // 0..511
      const float* base = pa.bias + (size_t)rr * 8 * 2048 + t * 8;
      uint4 a[8], b2[8];
#pragma unroll
      for (int i = 0; i < 8; i++) {
        const uint4* src = (const uint4*)(base + (size_t)i * 2048);
        a[i] = src[0]; b2[i] = src[1];
      }
      uint32_t (*wbuf)[4] = (uint32_t (*)[4])psm;   // [row][wave]
      int wv = t >> 6, ln = t & 63;
#pragma unroll
      for (int i = 0; i < 8; i++) {
        bool z = ((a[i].x << 1) == 0u) | ((a[i].y << 1) == 0u) |
                 ((a[i].z << 1) == 0u) | ((a[i].w << 1) == 0u) |
                 ((b2[i].x << 1) == 0u) | ((b2[i].y << 1) == 0u) |
                 ((b2[i].z << 1) == 0u) | ((b2[i].w << 1) == 0u);
        uint64_t m = __ballot(z);
        if (ln == 0) {
          uint32_t bits = 0;
#pragma unroll
          for (int c = 0; c < 8; c++)
            bits |= (uint32_t)(((m >> (8 * c)) & 0xFFull) != 0ull) << c;
          wbuf[i][wv] = bits;                  // chunks [wv*8, wv*8+8)
        }
      }
      __syncthreads();
      if (t < 8)
        pa.zrow[rr * 8 + t] = wbuf[t][0] | (wbuf[t][1] << 8) |
                              (wbuf[t][2] << 16) | (wbuf[t][3] << 24);
    } else {
      // ---- fmL = mask * log2(e) ----
      const float LOG2E = 1.44269504088896340736f;
#pragma unroll
      for (int i = 0; i < 16; i++) {
        int idx = i * 256 + t;
        pa.fmL[idx] = (float)pa.mask[idx] * LOG2E;
      }
    }
    return;
  }

  // ---- proj: y = x @ W^T + b, tile 128 s x 128 d ----
  // XCD swizzle: all 4 dtiles of group gi=(mat,mtile) get bids == gi (mod 8)
  // -> same XCD -> X tile fetched into one L2, read 4x from there.
  int xcd = bid & 7, j = bid >> 3;             // j in 0..47
  int gi = ((j >> 2) << 3) | xcd;              // group 0..95
  int dtile = j & 3;
  int mat = gi >> 5, mtile = gi & 31;
  int m0 = mtile * 128, n0 = dtile * 128;
  const float* X  = pa.X[mat];
  const float* Wt = pa.W[mat];
  const float* Bv = pa.Bv[mat];
  uint16_t*    O  = pa.O[mat];

  uint16_t (*Xs)[64] = (uint16_t (*)[64])psm;             // [128][64] 16 KB
  uint16_t (*Ws)[64] = (uint16_t (*)[64])(psm + 16384);   // [128][64] 16 KB

  int w = t >> 6, l = t & 63, lo = l & 15, g = l >> 4;
  int lr = l >> 4;          // 0..3 row-in-group (16 lanes per row)
  int lc = l & 15;          // 16B column chunk within the 256B row segment

  // coalesced staging bases: lane covers float cols [lc*4, lc*4+4)
  const float* Xp = X + (size_t)(m0 + w * 32 + lr) * 512 + lc * 4;
  const float* Wp = Wt + (size_t)(n0 + w * 32 + lr) * 512 + lc * 4;

  f32x4 acc[2][8];
#pragma unroll
  for (int st = 0; st < 2; st++)
#pragma unroll
    for (int dt = 0; dt < 8; dt++) acc[st][dt] = (f32x4){0.f, 0.f, 0.f, 0.f};

  float4 xa[8], wa2[8];
#pragma unroll
  for (int i = 0; i < 8; i++) xa[i] = *(const float4*)(Xp + (size_t)i * 4 * 512);
#pragma unroll
  for (int i = 0; i < 8; i++) wa2[i] = *(const float4*)(Wp + (size_t)i * 4 * 512);

  for (int kb = 0; kb < 8; kb++) {
    // pack current registers -> LDS (bf16), b64 per row-chunk.
    // row-major, 16B segs XOR'd by row&7.
#pragma unroll
    for (int i = 0; i < 8; i++) {
      int r = w * 32 + i * 4 + lr;
      int s0 = (lc >> 1) ^ (r & 7);
      uint2 pk{pk2(xa[i].x, xa[i].y), pk2(xa[i].z, xa[i].w)};
      *(uint2*)&Xs[r][s0 * 8 + (lc & 1) * 4] = pk;
    }
#pragma unroll
    for (int i = 0; i < 8; i++) {
      int r = w * 32 + i * 4 + lr;
      int s0 = (lc >> 1) ^ (r & 7);
      uint2 pk{pk2(wa2[i].x, wa2[i].y), pk2(wa2[i].z, wa2[i].w)};
      *(uint2*)&Ws[r][s0 * 8 + (lc & 1) * 4] = pk;
    }
    __syncthreads();
    if (kb < 7) {
      const float* Xn = Xp + (kb + 1) * 64;
      const float* Wn = Wp + (kb + 1) * 64;
#pragma unroll
      for (int i = 0; i < 8; i++) xa[i] = *(const float4*)(Xn + (size_t)i * 4 * 512);
#pragma unroll
      for (int i = 0; i < 8; i++) wa2[i] = *(const float4*)(Wn + (size_t)i * 4 * 512);
    }
#pragma unroll
    for (int kk = 0; kk < 2; kk++) {
      int seg = (kk * 4 + g) ^ (lo & 7);
      bf16x8 xf[2], wf[8];
#pragma unroll
      for (int st = 0; st < 2; st++)
        xf[st] = *(const bf16x8*)&Xs[w * 32 + st * 16 + lo][seg * 8];
#pragma unroll
      for (int dt = 0; dt < 8; dt++)
        wf[dt] = *(const bf16x8*)&Ws[dt * 16 + lo][seg * 8];
      if (mat < 2) {
#pragma unroll
        for (int st = 0; st < 2; st++)
#pragma unroll
          for (int dt = 0; dt < 8; dt++)
            acc[st][dt] = __builtin_amdgcn_mfma_f32_16x16x32_bf16(wf[dt], xf[st], acc[st][dt], 0, 0, 0);
      } else {
#pragma unroll
        for (int st = 0; st < 2; st++)
#pragma unroll
          for (int dt = 0; dt < 8; dt++)
            acc[st][dt] = __builtin_amdgcn_mfma_f32_16x16x32_bf16(xf[st], wf[dt], acc[st][dt], 0, 0, 0);
      }
    }
    __syncthreads();
  }

  if (mat < 2) {
    float scale = (mat == 0) ? 0.125f : 1.0f;
    float4 bv4[8];
#pragma unroll
    for (int dt = 0; dt < 8; dt++)
      bv4[dt] = *(const float4*)(Bv + n0 + dt * 16 + g * 4);
#pragma unroll
    for (int st = 0; st < 2; st++) {
      int ss = m0 + w * 32 + st * 16 + lo;
      int bb = ss >> 11, sIn = ss & 2047;
#pragma unroll
      for (int dt = 0; dt < 8; dt++) {
        int h2 = dtile * 2 + (dt >> 2);        // output head
        uint16_t* op = O + ((size_t)(bb * NH_ + h2) * S_ + sIn) * DK_ +
                       (dt & 3) * 16 + g * 4;
        float v0 = (acc[st][dt][0] + bv4[dt].x) * scale;
        float v1 = (acc[st][dt][1] + bv4[dt].y) * scale;
        float v2 = (acc[st][dt][2] + bv4[dt].z) * scale;
        float v3 = (acc[st][dt][3] + bv4[dt].w) * scale;
        uint2 pk{pk2(v0, v1), pk2(v2, v3)};
        *(uint2*)op = pk;
      }
    }
  } else {
    float bval[8];
#pragma unroll
    for (int dt = 0; dt < 8; dt++) bval[dt] = Bv[n0 + dt * 16 + lo];
#pragma unroll
    for (int st = 0; st < 2; st++) {
      int m = m0 + w * 32 + st * 16 + g * 4;
      int bb = m >> 11, sIn = m & 2047;
#pragma unroll
      for (int dt = 0; dt < 8; dt++) {
        int h2 = dtile * 2 + (dt >> 2);        // output head
        int dd = (dt & 3) * 16 + lo;
        float v0 = acc[st][dt][0] + bval[dt];
        float v1 = acc[st][dt][1] + bval[dt];
        float v2 = acc[st][dt][2] + bval[dt];
        float v3 = acc[st][dt][3] + bval[dt];
        uint2 pk{pk2(v0, v1), pk2(v2, v3)};
        *(uint2*)(O + ((size_t)(bb * NH_ + h2) * DK_ + dd) * S_ + sIn) = pk;
      }
    }
  }
}

// ---------------------------------------------------------------------------
// Kernel 2: flash attention (q-tile 64, grid 512, 2 blocks/CU).
// R12: TRUE counted-vmcnt pipeline (T3/T4). R9 still drained vmcnt(0) at
// every barrier — per m218, drain-0 ≈ no pipeline at all; the +38-73% came
// from never emptying the VMEM queue mid-loop. Now: triple-buffered K/V
// (3 x 16KB), prefetch distance 2, steady-state s_waitcnt vmcnt(4) (exactly
// one tile = 4 cp16 stays in flight across each barrier); only the last
// iteration drains. fm moved to LDS (8KB, preloaded by 2 cp16/wave) so the
// per-tile vmcnt ledger is exactly 4. Running global pointers cut per-tile
// address VALU. Compute + per-buffer layouts byte-identical to R11.
// ---------------------------------------------------------------------------
__global__ __launch_bounds__(256) void attn_kernel(
    const uint16_t* __restrict__ Qb, const uint16_t* __restrict__ Kb,
    const uint16_t* __restrict__ Vt, const uint32_t* __restrict__ zrow,
    const float* __restrict__ fmL, const float* __restrict__ bias,
    float* __restrict__ out) {
  int bid = blockIdx.x;
  int bh = bid & 15, qtile = bid >> 4;   // 512 blocks: bid%8 const per bh
  int b = bh >> 3, h = bh & 7;
  int q0 = qtile * 64;
  int t = threadIdx.x;
  int w = t >> 6, l = t & 63, lo = l & 15, g = l >> 4;

  // buf i at smem + i*16384: K[64][64] (8KB) | V[64][64] (8KB); fm at 49152.
  __shared__ __align__(16) char smem[57344];

  const uint16_t* Qh = Qb + (size_t)bh * S_ * DK_;
  const uint16_t* Kh = Kb + (size_t)bh * S_ * DK_;
  const uint16_t* Vh = Vt + (size_t)bh * DK_ * S_;

  // DMA: lane l -> LDS row w*16 + l/8, seg l&7; global seg = (l&7)^(row&7).
  int lrow = l >> 3, lseg = (l & 7) ^ lrow;
  const uint16_t* kbase = Kh + (size_t)(w * 16 + lrow) * DK_ + lseg * 8;
  const uint16_t* vbase = Vh + (size_t)(w * 16 + lrow) * S_ + lseg * 8;
  int kdo = w * 2048;          // K half dst byte offset (wave-uniform)
  int vdo = 8192 + w * 2048;   // V half

  // fm preload: 8 KB = 2 cp16 per wave (must be the FIRST cp16s issued:
  // they are the oldest entries in the vmcnt ledger, retired by the first
  // vmcnt(4)).
  float* fmlds = (float*)(smem + 49152);
  const float* fmG = fmL + b * S_;
  cp16(fmG + w * 256 + l * 4, smem + 49152 + w * 1024);
  cp16(fmG + 1024 + w * 256 + l * 4, smem + 49152 + 4096 + w * 1024);

  // stage tiles 0 and 1 (distance-2 prologue)
  auto stage = [&](const uint16_t* kp, const uint16_t* vp, uint32_t bufo) {
    cp16(kp, smem + bufo + kdo);
    cp16(kp + 512, smem + bufo + kdo + 1024);
    cp16(vp, smem + bufo + vdo);
    cp16(vp + 8 * S_, smem + bufo + vdo + 1024);
  };
  stage(kbase, vbase, 0);
  stage(kbase + 4096, vbase + 64, 16384);
  const uint16_t* kpS = kbase + 8192;   // running src for stage(kb+2)
  const uint16_t* vpS = vbase + 128;

  // block-uniform zero-bias mask (OR over this block's 64 q rows)
  uint32_t zall = zrow[(b << 11) + q0 + l];
#pragma unroll
  for (int s = 1; s < 64; s <<= 1) zall |= __shfl_xor(zall, s);

  // Register-resident Q fragments (B-operand of QK), 4 q-subtiles x K=64.
  bf16x8 qf[4][2];
#pragma unroll
  for (int qt = 0; qt < 4; qt++)
#pragma unroll
    for (int kk = 0; kk < 2; kk++)
      qf[qt][kk] = *(const bf16x8*)(Qh + (size_t)(q0 + qt * 16 + lo) * DK_ + kk * 32 + g * 8);

  f32x4 o[4][4];
#pragma unroll
  for (int dt = 0; dt < 4; dt++)
#pragma unroll
    for (int qt = 0; qt < 4; qt++) o[dt][qt] = (f32x4){0.f, 0.f, 0.f, 0.f};
  f32x4 tsa[4];
#pragma unroll
  for (int qt = 0; qt < 4; qt++) tsa[qt] = (f32x4){0.f, 0.f, 0.f, 0.f};
  const s16x4 vone = {(short)0x3F80, (short)0x3F80, (short)0x3F80, (short)0x3F80};

  const float LOG2E = 1.44269504088896340736f;

  uint32_t oA = 0, oB = 16384, oC = 32768;   // compute / in-flight / stage

  for (int kb = 0; kb < 32; kb++) {
    int k0 = kb * 64;
    // steady state: 8 cp16 outstanding (tiles kb, kb+1). vmcnt(4) retires
    // tile kb (+ fm/q prologue loads at kb=0); tile kb+1 stays in flight
    // across the barrier and this tile's whole compute. Never drains
    // mid-loop (T4) — only kb=31 waits to zero.
    if (kb < 31) asm volatile("s_waitcnt vmcnt(4)" ::: "memory");
    else         asm volatile("s_waitcnt vmcnt(0)" ::: "memory");
    __builtin_amdgcn_s_barrier();               // publish tile kb to all waves
    if (kb + 2 < 32) {                          // stage tile kb+2
      stage(kpS, vpS, oC);
      kpS += 4096; vpS += 64;
    }
    __builtin_amdgcn_sched_barrier(0);          // pin: no ds_read above barrier

    const uint16_t* KsT = (const uint16_t*)(smem + oA);
    const uint16_t* VsT = (const uint16_t*)(smem + oA + 8192);

    // V^T A-frags for PV
    s16x4 vf[4];
    {
      int s = (2 * w + (g >> 1)) ^ (lo & 7);
      int off = s * 8 + (g & 1) * 4;
#pragma unroll
      for (int dt = 0; dt < 4; dt++)
        vf[dt] = *(const s16x4*)(VsT + (dt * 16 + lo) * 64 + off);
    }
    // K A-frags (this wave's 16 k-rows)
    bf16x8 kf[2];
#pragma unroll
    for (int kk = 0; kk < 2; kk++) {
      int s = (kk * 4 + g) ^ (lo & 7);
      kf[kk] = *(const bf16x8*)(KsT + (w * 16 + lo) * 64 + s * 8);
    }

    // S^T = K * Q^T : lane holds S[k = w*16+g*4+r][q = qt*16+lo]
    f32x4 c[4];
#pragma unroll
    for (int qt = 0; qt < 4; qt++) {
      f32x4 z = {0.f, 0.f, 0.f, 0.f};
      z = __builtin_amdgcn_mfma_f32_16x16x32_bf16(kf[0], qf[qt][0], z, 0, 0, 0);
      c[qt] = __builtin_amdgcn_mfma_f32_16x16x32_bf16(kf[1], qf[qt][1], z, 0, 0, 0);
    }

    float4 mv4 = *(const float4*)(fmlds + kb * 64 + w * 16 + g * 4);
    s16x4 pf[4];
    if (((zall >> kb) & 1u) == 0u) {   // no zero bias in this 64k chunk
#pragma unroll
      for (int qt = 0; qt < 4; qt++) {
        float p0 = __builtin_amdgcn_exp2f(__builtin_fmaf(c[qt][0], LOG2E, mv4.x));
        float p1 = __builtin_amdgcn_exp2f(__builtin_fmaf(c[qt][1], LOG2E, mv4.y));
        float p2 = __builtin_amdgcn_exp2f(__builtin_fmaf(c[qt][2], LOG2E, mv4.z));
        float p3 = __builtin_amdgcn_exp2f(__builtin_fmaf(c[qt][3], LOG2E, mv4.w));
        union { s16x4 v; uint32_t u[2]; } uu;
        uu.u[0] = pk2(p0, p1);
        uu.u[1] = pk2(p2, p3);
        pf[qt] = uu.v;
      }
    } else {                           // rare: bias==0 -> weight 0
#pragma unroll
      for (int qt = 0; qt < 4; qt++) {
        float4 bz = *(const float4*)(bias + ((size_t)(b * S_ + q0 + qt * 16 + lo)) * S_ + k0 + w * 16 + g * 4);
        float p0 = (bz.x == 0.f) ? 0.f : __builtin_amdgcn_exp2f(__builtin_fmaf(c[qt][0], LOG2E, mv4.x));
        float p1 = (bz.y == 0.f) ? 0.f : __builtin_amdgcn_exp2f(__builtin_fmaf(c[qt][1], LOG2E, mv4.y));
        float p2 = (bz.z == 0.f) ? 0.f : __builtin_amdgcn_exp2f(__builtin_fmaf(c[qt][2], LOG2E, mv4.z));
        float p3 = (bz.w == 0.f) ? 0.f : __builtin_amdgcn_exp2f(__builtin_fmaf(c[qt][3], LOG2E, mv4.w));
        union { s16x4 v; uint32_t u[2]; } uu;
        uu.u[0] = pk2(p0, p1);
        uu.u[1] = pk2(p2, p3);
        pf[qt] = uu.v;
      }
    }

    // row-sum via matrix pipe: tsa[qt][r] = sum_k pf[k][q=lo] (all r equal)
#pragma unroll
    for (int qt = 0; qt < 4; qt++)
      tsa[qt] = mfma_k16(vone, pf[qt], tsa[qt]);

    // PV: o[dt][qt] lane holds O[q=qt*16+lo][d=dt*16+g*4+r]
#pragma unroll
    for (int dt = 0; dt < 4; dt++)
#pragma unroll
      for (int qt = 0; qt < 4; qt++)
        o[dt][qt] = mfma_k16(vf[dt], pf[qt], o[dt][qt]);

    // rotate buffers
    uint32_t tmp = oA; oA = oB; oB = oC; oC = tmp;
  }

  // ---- epilogue: reduce 4 wave-partials, normalize, store (2 q-halves) ----
  float* OT = (float*)smem;               // [64 d][33] floats (8448 B)
  float* LS = (float*)(smem + 8448);      // [4 w][4 qt][16 lo] (1 KB)
  __syncthreads();                        // main-loop LDS reads complete
  if (g == 0) {
#pragma unroll
    for (int qt = 0; qt < 4; qt++) LS[(w * 4 + qt) * 16 + lo] = tsa[qt][0];
  }
#pragma unroll
  for (int qh = 0; qh < 2; qh++) {
#pragma unroll
    for (int ww = 0; ww < 4; ww++) {
      if (w == ww) {
#pragma unroll
        for (int dt = 0; dt < 4; dt++)
#pragma unroll
          for (int qt = 0; qt < 2; qt++)
#pragma unroll
            for (int r = 0; r < 4; r++) {
              int idx = (dt * 16 + g * 4 + r) * 33 + qt * 16 + lo;
              float val = o[dt][qh * 2 + qt][r];
              if (ww == 0) OT[idx] = val;
              else         OT[idx] += val;
            }
      }
      __syncthreads();
    }
    {
      int q = t >> 3, dseg = (t & 7) * 8;   // q in [0,32), 8 d per thread
      int qt2 = qh * 2 + (q >> 4), lo2 = q & 15;
      float lsum = LS[(0 * 4 + qt2) * 16 + lo2] + LS[(1 * 4 + qt2) * 16 + lo2] +
                   LS[(2 * 4 + qt2) * 16 + lo2] + LS[(3 * 4 + qt2) * 16 + lo2];
      float linv = 1.0f / fmaxf(lsum, 1e-30f);
      float* ob = out + ((size_t)(b * S_ + q0 + qh * 32 + q)) * H_ + h * DK_ + dseg;
#pragma unroll
      for (int i = 0; i < 2; i++) {
        float4 v;
        v.x = OT[(dseg + i * 4 + 0) * 33 + q] * linv;
        v.y = OT[(dseg + i * 4 + 1) * 33 + q] * linv;
        v.z = OT[(dseg + i * 4 + 2) * 33 + q] * linv;
        v.w = OT[(dseg + i * 4 + 3) * 33 + q] * linv;
        *(float4*)(ob + i * 4) = v;
      }
    }
    __syncthreads();                      // OT reads done before next overwrite
  }
}

// ---------------------------------------------------------------------------
extern "C" void kernel_launch(void* const* d_in, const int* in_sizes, int n_in,
                              void* d_out, int out_size, void* d_ws, size_t ws_size,
                              hipStream_t stream) {
  const float* query = (const float*)d_in[0];
  const float* key   = (const float*)d_in[1];
  const float* value = (const float*)d_in[2];
  const float* bias  = (const float*)d_in[3];
  const int*   mask  = (const int*)d_in[4];
  const float* Wq = (const float*)d_in[5];
  const float* bq = (const float*)d_in[6];
  const float* Wk = (const float*)d_in[7];
  const float* bk = (const float*)d_in[8];
  const float* Wv = (const float*)d_in[9];
  const float* bv = (const float*)d_in[10];

  char* ws = (char*)d_ws;
  uint32_t* zrow = (uint32_t*)ws;                             // 16 KB
  float*    fmL  = (float*)(ws + 16384);                      // 16 KB
  uint16_t* Qb = (uint16_t*)(ws + (size_t)(1 << 20));         // 4 MB
  uint16_t* Kb = (uint16_t*)(ws + (size_t)(5 << 20));         // 4 MB
  uint16_t* Vt = (uint16_t*)(ws + (size_t)(9 << 20));         // 4 MB

  ProjArgs pa;
  pa.X[0] = query; pa.X[1] = key; pa.X[2] = value;
  pa.W[0] = Wq;    pa.W[1] = Wk;  pa.W[2] = Wv;
  pa.Bv[0] = bq;   pa.Bv[1] = bk; pa.Bv[2] = bv;
  pa.O[0] = Qb;    pa.O[1] = Kb;  pa.O[2] = Vt;
  pa.bias = bias;  pa.mask = mask;
  pa.zrow = zrow;  pa.fmL = fmL;

  prep_proj_kernel<<<897, 256, 0, stream>>>(pa);

  attn_kernel<<<512, 256, 0, stream>>>(Qb, Kb, Vt, zrow, fmL, bias, (float*)d_out);
}